// Round 8
// baseline (383.598 us; speedup 1.0000x reference)
//
#include <hip/hip_runtime.h>

// Problem constants (static per reference)
#define NHEAD 8
#define NPOINT 4
#define NLVL 6
#define CDIM 256
#define BSZ 8
#define NQRY 4096
#define NVAL 10752

typedef __attribute__((ext_vector_type(8))) short short8;   // 8 bf16 = 4 VGPRs
typedef __attribute__((ext_vector_type(4))) float floatx4;  // MFMA acc
typedef __attribute__((ext_vector_type(2))) float float2v;  // packed f32 (v_pk_fma_f32)

__device__ __forceinline__ unsigned short f2bf(float f) {
    unsigned u = __float_as_uint(f);
    return (unsigned short)((u + 0x7FFFu + ((u >> 16) & 1u)) >> 16);  // RNE
}
__device__ __forceinline__ unsigned pack2(float a, float b) {
    return (unsigned)f2bf(a) | ((unsigned)f2bf(b) << 16);
}
__device__ __forceinline__ float blo(unsigned u) { return __uint_as_float(u << 16); }
__device__ __forceinline__ float bhi(unsigned u) { return __uint_as_float(u & 0xffff0000u); }

// async global -> LDS, 16 B per lane (global_load_lds_dwordx4).
// lds dest must be wave-uniform base; HW writes base + lane*16.
__device__ __forceinline__ void gload16(const void* g, void* l) {
    __builtin_amdgcn_global_load_lds(
        (const __attribute__((address_space(1))) unsigned int*)g,
        (__attribute__((address_space(3))) unsigned int*)l, 16, 0, 0);
}

// ---- prep: W matrices -> bf16, transposed [N][256] -------------------------
// Wt rows: [0,256) = W_val^T; [256,832) = [W_off|W_attn]^T; [832,1088) = W_out^T
__global__ __launch_bounds__(256) void prep_w(
    const float* __restrict__ Wv, const float* __restrict__ Woff,
    const float* __restrict__ Wattn, const float* __restrict__ Wo,
    unsigned short* __restrict__ Wt)
{
    const int id = blockIdx.x * 256 + threadIdx.x;   // < 1088*256
    const int n = id >> 8, k = id & 255;
    float val;
    if (n < 256) val = Wv[k * 256 + n];
    else if (n < 832) {
        const int nn = n - 256;
        val = (nn < 384) ? Woff[k * 384 + nn] : Wattn[k * 192 + (nn - 384)];
    } else val = Wo[k * 256 + (n - 832)];
    Wt[id] = f2bf(val);
}

// ---- q = bf16(query + query_pos) ------------------------------------------
__global__ __launch_bounds__(256) void q_conv(
    const float* __restrict__ query, const float* __restrict__ qpos,
    unsigned short* __restrict__ qbf)
{
    const long i = ((long)blockIdx.x * 256 + threadIdx.x) * 4;
    const float4 a = *(const float4*)(query + i);
    const float4 b = *(const float4*)(qpos + i);
    ushort4 r;
    r.x = f2bf(a.x + b.x); r.y = f2bf(a.y + b.y);
    r.z = f2bf(a.z + b.z); r.w = f2bf(a.w + b.w);
    *(ushort4*)(qbf + i) = r;
}

// ---- bf16 MFMA GEMM: C[M,N] = A[M,256] @ Bt[N,256]^T + bias ---------------
// 512 thr = 8 waves; block tile 128 x BN; wave tile 64 x (BN/4).
// BK=64; LDS [2] double-buffered, linear [row][64] bf16 (128 B rows),
// chunk-XOR swizzled: phys chunk = logical chunk ^ (row & 7)  (chunk = 16 B).
//
// 2-PHASE PIPELINE (T3/T4 minimum form): per k-step, issue NEXT tile's stage
// (DMA for bf16 paths; global->reg loads for fp32 A) BEFORE computing the
// current tile; ds_write of A regs AFTER the MFMAs (T14 split); ONE barrier
// per k-step. The compiler's vmcnt(0) before s_barrier then drains loads
// issued a whole compute-phase earlier -> staging latency hidden.
//
// AMODE: 0 = A fp32 (reg-stage + cvt), 1 = A bf16 (async DMA).
// OPERAND-SWAPPED MFMA: acc = mfma(bfr, af, acc) -> lane holds 4 consecutive
// output cols of one row: vectorized float4/ushort4 epilogue.
// VTRANS: C -> bf16 [b][h][pos][32]. RESID: += resid fp32. SPLITB: bias2 at
// col>=384.
template<int BN, int AMODE, int VTRANS, int RESID, int SPLITB>
__global__ __launch_bounds__(512) void gemm_mfma(
    const void* __restrict__ Av, const unsigned short* __restrict__ Bt,
    const float* __restrict__ bias, const float* __restrict__ bias2,
    const float* __restrict__ resid, void* __restrict__ Cv,
    int M, int Ntot)
{
    constexpr int BK = 64, BMt = 128;
    constexpr int WN = BN / 4, NT = WN / 16;
    constexpr int ACH = BMt * (BK / 8);     // A 16B-chunks = 1024
    constexpr int BCH = BN * (BK / 8);      // B 16B-chunks
    constexpr int NCH = ACH + BCH;
    __shared__ char smem[2][NCH * 16];      // per buf: A [0,16K) B [16K,..)
    const int tid = threadIdx.x;
    const int bm = blockIdx.y * BMt;
    const int bcol = blockIdx.x * BN;
    const int wid = tid >> 6, lane = tid & 63;
    const int wm = (wid >> 2) * 64, wn = (wid & 3) * WN;
    const int lm = lane & 15;

    floatx4 acc[4][NT];
#pragma unroll
    for (int i = 0; i < 4; ++i)
#pragma unroll
        for (int j = 0; j < NT; ++j) acc[i][j] = (floatx4)0.0f;

    float4 ra[2][2];   // AMODE==0 in-flight A tile (T14 issue-early/write-late)

    auto ALOAD = [&](int k0) {
#pragma unroll
        for (int j = 0; j < 2; ++j) {
            const int g = j * 512 + tid;
            const int row = g >> 3, c = g & 7;
            const float* p = (const float*)Av + (long)(bm + row) * 256 + k0 + c * 8;
            ra[j][0] = *(const float4*)p;
            ra[j][1] = *(const float4*)(p + 4);
        }
    };
    auto AWRITE = [&](char* sm) {
#pragma unroll
        for (int j = 0; j < 2; ++j) {
            const int g = j * 512 + tid;
            const int row = g >> 3, c = g & 7;
            uint4 v;
            v.x = pack2(ra[j][0].x, ra[j][0].y); v.y = pack2(ra[j][0].z, ra[j][0].w);
            v.z = pack2(ra[j][1].x, ra[j][1].y); v.w = pack2(ra[j][1].z, ra[j][1].w);
            *(uint4*)(sm + row * 128 + ((c ^ (row & 7)) << 4)) = v;
        }
    };
    auto BSTAGE = [&](int k0, char* sm) {
        if (AMODE == 1) {
            const unsigned short* A = (const unsigned short*)Av;
            constexpr int NI = NCH / 512;
#pragma unroll
            for (int j = 0; j < NI; ++j) {
                const int cbase = (wid * NI + j) * 64;
                const int g = cbase + lane;
                const unsigned short* src;
                if (cbase < ACH) {          // wave-uniform branch (64 | ACH)
                    const int row = g >> 3, c = (g & 7) ^ (row & 7);
                    src = A + (long)(bm + row) * 256 + k0 + c * 8;
                } else {
                    const int g2 = g - ACH;
                    const int row = g2 >> 3, c = (g2 & 7) ^ (row & 7);
                    src = Bt + (long)(bcol + row) * 256 + k0 + c * 8;
                }
                gload16(src, sm + cbase * 16);
            }
        } else {
            constexpr int NIB = BCH / 512;
#pragma unroll
            for (int j = 0; j < NIB; ++j) {
                const int cbase = (wid * NIB + j) * 64;
                const int g2 = cbase + lane;
                const int row = g2 >> 3, c = (g2 & 7) ^ (row & 7);
                gload16(Bt + (long)(bcol + row) * 256 + k0 + c * 8,
                        sm + ACH * 16 + cbase * 16);
            }
        }
    };

    // prologue: fill buffer 0
    if (AMODE == 0) ALOAD(0);
    BSTAGE(0, smem[0]);
    if (AMODE == 0) AWRITE(smem[0]);
    __syncthreads();

    int cur = 0;
    for (int t = 0; t < 4; ++t) {           // 256 / BK = 4 k-steps
        if (t < 3) {
            if (AMODE == 0) ALOAD((t + 1) * BK);
            BSTAGE((t + 1) * BK, smem[cur ^ 1]);
        }
        char* sA = smem[cur];
        char* sB = smem[cur] + ACH * 16;
#pragma unroll
        for (int kk = 0; kk < 2; ++kk) {
            const int cc = kk * 4 + (lane >> 4);   // logical 16B chunk in row
            short8 af[4], bfr[NT];
#pragma unroll
            for (int i = 0; i < 4; ++i) {
                const int row = wm + i * 16 + lm;
                af[i] = *(const short8*)(sA + row * 128 + ((cc ^ (row & 7)) << 4));
            }
#pragma unroll
            for (int j = 0; j < NT; ++j) {
                const int row = wn + j * 16 + lm;
                bfr[j] = *(const short8*)(sB + row * 128 + ((cc ^ (row & 7)) << 4));
            }
#pragma unroll
            for (int i = 0; i < 4; ++i)
#pragma unroll
                for (int j = 0; j < NT; ++j)
                    acc[i][j] = __builtin_amdgcn_mfma_f32_16x16x32_bf16(bfr[j], af[i], acc[i][j], 0, 0, 0);
        }
        if (t < 3 && AMODE == 0) AWRITE(smem[cur ^ 1]);
        __syncthreads();
        cur ^= 1;
    }

    // ---- vectorized epilogue: lane holds 4 consecutive cols of one row ----
    const int qrow = (lane >> 4) * 4;
#pragma unroll
    for (int j = 0; j < NT; ++j) {
        const int colg = bcol + wn + j * 16 + qrow;   // cols colg .. colg+3
        float4 bv4;
        if (SPLITB && colg >= 384) bv4 = *(const float4*)(bias2 + colg - 384);
        else                       bv4 = *(const float4*)(bias + colg);
#pragma unroll
        for (int i = 0; i < 4; ++i) {
            const int rowl = wm + i * 16 + lm;
            const int rowg = bm + rowl;
            float v0 = acc[i][j][0] + bv4.x;
            float v1 = acc[i][j][1] + bv4.y;
            float v2 = acc[i][j][2] + bv4.z;
            float v3 = acc[i][j][3] + bv4.w;
            if (VTRANS) {
                // bf16 v in [b][h][pos][32]; 128 | NVAL so block is one batch.
                // 4 consecutive cols stay within one h-plane (4 | 32).
                const int b = bm / NVAL;
                const int pos = bm - b * NVAL + rowl;
                const int h = colg >> 5, d = colg & 31;
                ushort4 o;
                o.x = f2bf(v0); o.y = f2bf(v1); o.z = f2bf(v2); o.w = f2bf(v3);
                *(ushort4*)&((unsigned short*)Cv)[
                    (((long)(b * NHEAD + h)) * NVAL + pos) * 32 + d] = o;
            } else {
                if (RESID) {
                    const float4 rr = *(const float4*)(resid + (long)rowg * 256 + colg);
                    v0 += rr.x; v1 += rr.y; v2 += rr.z; v3 += rr.w;
                }
                float4 o; o.x = v0; o.y = v1; o.z = v2; o.w = v3;
                *(float4*)&((float*)Cv)[(long)rowg * Ntot + colg] = o;
            }
        }
    }
}

// ---- deformable sampling (wave per query, bf16 v, bf16 out) ----------------
// 256 thr = 4 waves = 4 queries. lane: head h = lane>>3, li = lane&7.
// v: bf16 [b][h][pos][32]; oa row: [off(384) | attn(192)] fp32.
// (XCD-batch pinning tried in R7: FETCH -33% but dur +6% -> reverted; the
// kernel is latency-bound and pinning hotspots one XCD's L2 on 5.5MB.)
//
// Two-phase. Phase 1: each lane owns 3 samples of its head; softmax via 8-lane
// shfl tree; per sample compute geometry ONCE and store a 24-B record
// {w0l,w1l,w0r,w1r, byteoff_row0, byteoff_row1} in LDS. The two x-corners of a
// bilinear row are adjacent 64-B blocks -> one 128-B contiguous region starting
// at xb=clamp(x0,0,W-2); corner weights re-assigned so the extra column gets 0.
// Phase 2: per (lp,row) ONE dwordx4 gather (8 lanes x 16B = 128B: lanes 0-3 =
// left corner ch li*8..+7, lanes 4-7 = right corner). Corner-side partials
// summed at the end via shfl_xor(4).
__global__ __launch_bounds__(256) void ms_sample4(
    const unsigned short* __restrict__ v,
    const float* __restrict__ oa,
    const float* __restrict__ refp,
    unsigned short* __restrict__ outi)
{
    __shared__ float s_rec[4][192 * 6];   // [wave][ (lp*8+h)*6 ] : 4x4608 B
    __shared__ float s_ref[4][12];
    const int tid = threadIdx.x;
    const int w = tid >> 6;
    const int lane = tid & 63;
    const int bq = blockIdx.x * 4 + w;
    const int b = bq >> 12;

    if (lane < 12) s_ref[w][lane] = refp[(long)bq * 12 + lane];
    __syncthreads();

    const int h = lane >> 3;
    const int li = lane & 7;
    const float* oarow = oa + (long)bq * 576;

    // ---- phase 1a: softmax over this head's 24 logits (3 per lane) --------
    const float* lgp = oarow + 384 + h * 24 + li * 3;
    const float lg0 = lgp[0], lg1 = lgp[1], lg2 = lgp[2];
    float mx = fmaxf(lg0, fmaxf(lg1, lg2));
    mx = fmaxf(mx, __shfl_xor(mx, 1));
    mx = fmaxf(mx, __shfl_xor(mx, 2));
    mx = fmaxf(mx, __shfl_xor(mx, 4));
    const float e0 = __expf(lg0 - mx);
    const float e1 = __expf(lg1 - mx);
    const float e2 = __expf(lg2 - mx);
    float den = e0 + e1 + e2;
    den += __shfl_xor(den, 1);
    den += __shfl_xor(den, 2);
    den += __shfl_xor(den, 4);
    const float inv = 1.0f / den;
    const float aw_[3] = {e0 * inv, e1 * inv, e2 * inv};

    // ---- phase 1b: geometry + fused weights for 3 owned samples -----------
    const float* offp = oarow + (h * 24 + li * 3) * 2;   // 8-B aligned
    const float2v od0 = *(const float2v*)(offp);
    const float2v od1 = *(const float2v*)(offp + 2);
    const float2v od2 = *(const float2v*)(offp + 4);

#pragma unroll
    for (int k = 0; k < 3; ++k) {
        const int lp = li * 3 + k;
        const int l = lp >> 2;
        const int sh = (l >= 3) ? (l - 3) : l;
        const int W = 64 >> sh;
        const int base = ((l >= 3) ? 5376 : 0)
                       + ((sh >= 1) ? 4096 : 0)
                       + ((sh >= 2) ? 1024 : 0);
        const float Wf = (float)W;
        const float ox = (k == 0) ? od0.x : (k == 1) ? od1.x : od2.x;
        const float oy = (k == 0) ? od0.y : (k == 1) ? od1.y : od2.y;
        const float rx = s_ref[w][l * 2 + 0];
        const float ry = s_ref[w][l * 2 + 1];
        const float x = rx * Wf + ox - 0.5f;   // == ((rx + ox/W)*W - 0.5), pow2
        const float y = ry * Wf + oy - 0.5f;
        const float xf = floorf(x), yf = floorf(y);
        const int x0 = (int)xf, y0 = (int)yf;
        const float lx = x - xf, ly = y - yf;
        const float wx0 = (x0 >= 0 && x0 < W)      ? (1.f - lx) : 0.f;
        const float wx1 = (x0 >= -1 && x0 < W - 1) ? lx         : 0.f;
        const float wy0 = (y0 >= 0 && y0 < W)      ? (1.f - ly) : 0.f;
        const float wy1 = (y0 >= -1 && y0 < W - 1) ? ly         : 0.f;
        const int y0c = min(max(y0, 0), W - 1);
        const int y1c = min(max(y0 + 1, 0), W - 1);
        // x: load 128-B region [xb, xb+1]; re-assign corner weights so the
        // padded column carries weight 0 (OOB corners have wx==0 already).
        const int xb = min(max(x0, 0), W - 2);
        const float wl = (xb == x0) ? wx0 : ((xb == x0 + 1) ? wx1 : 0.f);
        const float wr = (xb == x0) ? wx1 : ((xb == x0 - 1) ? wx0 : 0.f);
        const float aw = aw_[k];
        const float awl = aw * wl, awr = aw * wr;
        float* r = &s_rec[w][((lp << 3) + h) * 6];
        float2v wlv, wrv;
        wlv.x = awl * wy0; wlv.y = awl * wy1;   // (row0, row1) left corner
        wrv.x = awr * wy0; wrv.y = awr * wy1;   // (row0, row1) right corner
        *(float2v*)(r)     = wlv;
        *(float2v*)(r + 2) = wrv;
        uint2 pk;
        pk.x = (unsigned)(base + y0c * W + xb) * 64u;   // byte offset, row0
        pk.y = (unsigned)(base + y1c * W + xb) * 64u;   // byte offset, row1
        *(uint2*)(r + 4) = pk;
    }
    __syncthreads();

    // ---- phase 2: gather + accumulate (packed f32) ------------------------
    // lane carries 8 channels [(li&3)*8 .. +7] of ONE corner side (li<4 left).
    const unsigned lane_base =
        (unsigned)((b * NHEAD + h) * NVAL) * 64u + (unsigned)li * 16u;
    const char* vbase = (const char*)v;
    const int sel = (li >> 2) * 2;            // weight pair: 0=left, 2=right
    const float* rp0 = &s_rec[w][h * 6];
    float2v a01 = {0.f, 0.f}, a23 = {0.f, 0.f};
    float2v a45 = {0.f, 0.f}, a67 = {0.f, 0.f};

#pragma unroll 8
    for (int lp = 0; lp < NLVL * NPOINT; ++lp) {
        const float* rp = rp0 + lp * 48;
        const float2v wv = *(const float2v*)(rp + sel);   // (w_row0, w_row1)
        const uint2 off = *(const uint2*)(rp + 4);
        const uint4 u0 = *(const uint4*)(vbase + (lane_base + off.x));
        const uint4 u1 = *(const uint4*)(vbase + (lane_base + off.y));
        float2v c;
        c.x = blo(u0.x); c.y = bhi(u0.x); a01 += wv.x * c;
        c.x = blo(u0.y); c.y = bhi(u0.y); a23 += wv.x * c;
        c.x = blo(u0.z); c.y = bhi(u0.z); a45 += wv.x * c;
        c.x = blo(u0.w); c.y = bhi(u0.w); a67 += wv.x * c;
        c.x = blo(u1.x); c.y = bhi(u1.x); a01 += wv.y * c;
        c.x = blo(u1.y); c.y = bhi(u1.y); a23 += wv.y * c;
        c.x = blo(u1.z); c.y = bhi(u1.z); a45 += wv.y * c;
        c.x = blo(u1.w); c.y = bhi(u1.w); a67 += wv.y * c;
    }

    // combine left/right corner partials (same channels in lane li and li^4)
    a01.x += __shfl_xor(a01.x, 4); a01.y += __shfl_xor(a01.y, 4);
    a23.x += __shfl_xor(a23.x, 4); a23.y += __shfl_xor(a23.y, 4);
    a45.x += __shfl_xor(a45.x, 4); a45.y += __shfl_xor(a45.y, 4);
    a67.x += __shfl_xor(a67.x, 4); a67.y += __shfl_xor(a67.y, 4);

    // output: lane li<4 writes ch (li&3)*8 + 0..3, lane li>=4 writes +4..7
    const int hi = li >> 2;
    const float o0 = hi ? a45.x : a01.x;
    const float o1 = hi ? a45.y : a01.y;
    const float o2 = hi ? a67.x : a23.x;
    const float o3 = hi ? a67.y : a23.y;
    ushort4 o;
    o.x = f2bf(o0); o.y = f2bf(o1); o.z = f2bf(o2); o.w = f2bf(o3);
    const int d = (li & 3) * 8 + hi * 4;
    *(ushort4*)(outi + (long)bq * CDIM + h * 32 + d) = o;
}

// ---------------- launch ---------------------------------------------------
extern "C" void kernel_launch(void* const* d_in, const int* in_sizes, int n_in,
                              void* d_out, int out_size, void* d_ws, size_t ws_size,
                              hipStream_t stream) {
    const float* query     = (const float*)d_in[0];
    const float* query_pos = (const float*)d_in[1];
    const float* value     = (const float*)d_in[2];
    const float* refp      = (const float*)d_in[3];
    // d_in[4] = spatial_shapes (static, hard-coded)
    const float* W_off  = (const float*)d_in[5];
    const float* b_off  = (const float*)d_in[6];
    const float* W_attn = (const float*)d_in[7];
    const float* b_attn = (const float*)d_in[8];
    const float* W_val  = (const float*)d_in[9];
    const float* b_val  = (const float*)d_in[10];
    const float* W_out  = (const float*)d_in[11];
    const float* b_out  = (const float*)d_in[12];
    float* out = (float*)d_out;

    // workspace: all bf16 buffers as ushort
    unsigned short* v_bf = (unsigned short*)d_ws;            // 86016*256 bf16 [b][h][pos][32]
    unsigned short* q_bf = v_bf + (long)86016 * 256;         // 32768*256 bf16
    unsigned short* Wt   = q_bf + (long)32768 * 256;         // 1088*256 bf16 (transposed W's)
    float* oa_ws = (float*)(Wt + (long)1088 * 256);          // 32768*576 fp32 [off|attn]
    unsigned short* i_bf = (unsigned short*)(oa_ws + (long)32768 * 576);  // 32768*256 bf16

    const int MV = BSZ * NVAL;   // 86016
    const int MQ = BSZ * NQRY;   // 32768

    // W -> bf16 transposed
    prep_w<<<1088, 256, 0, stream>>>(W_val, W_off, W_attn, W_out, Wt);
    // q = bf16(query + query_pos)  (16 MB bf16; L2/L3-resident for gemm2's 3 col-blocks)
    q_conv<<<(MQ * CDIM / 4) / 256, 256, 0, stream>>>(query, query_pos, q_bf);
    // v = value @ W_val + b_val -> bf16 [b][h][pos][32]   (A fp32 in-kernel cvt)
    gemm_mfma<256, 0, 1, 0, 0><<<dim3(1, MV / 128), 512, 0, stream>>>(
        value, Wt, b_val, nullptr, nullptr, v_bf, MV, 256);
    // [off|attn] = q @ [W_off|W_attn] + [b_off|b_attn]  (fp32 out, N=576)
    gemm_mfma<192, 1, 0, 0, 1><<<dim3(3, MQ / 128), 512, 0, stream>>>(
        q_bf, Wt + (long)256 * 256, b_off, b_attn, nullptr, oa_ws, MQ, 576);
    // deformable sampling -> interm bf16
    ms_sample4<<<MQ / 4, 256, 0, stream>>>(v_bf, oa_ws, refp, i_bf);
    // out = interm @ W_out + b_out + query
    gemm_mfma<256, 1, 0, 1, 0><<<dim3(1, MQ / 128), 512, 0, stream>>>(
        i_bf, Wt + (long)832 * 256, b_out, nullptr, query, out, MQ, 256);
}

// Round 9
// 363.076 us; speedup vs baseline: 1.0565x; 1.0565x over previous
//
#include <hip/hip_runtime.h>

// Problem constants (static per reference)
#define NHEAD 8
#define NPOINT 4
#define NLVL 6
#define CDIM 256
#define BSZ 8
#define NQRY 4096
#define NVAL 10752

typedef __attribute__((ext_vector_type(8))) short short8;   // 8 bf16 = 4 VGPRs
typedef __attribute__((ext_vector_type(4))) float floatx4;  // MFMA acc
typedef __attribute__((ext_vector_type(2))) float float2v;  // packed f32 (v_pk_fma_f32)

__device__ __forceinline__ unsigned short f2bf(float f) {
    unsigned u = __float_as_uint(f);
    return (unsigned short)((u + 0x7FFFu + ((u >> 16) & 1u)) >> 16);  // RNE
}
__device__ __forceinline__ unsigned pack2(float a, float b) {
    return (unsigned)f2bf(a) | ((unsigned)f2bf(b) << 16);
}
__device__ __forceinline__ float blo(unsigned u) { return __uint_as_float(u << 16); }
__device__ __forceinline__ float bhi(unsigned u) { return __uint_as_float(u & 0xffff0000u); }

// async global -> LDS, 16 B per lane (global_load_lds_dwordx4).
// lds dest must be wave-uniform base; HW writes base + lane*16.
__device__ __forceinline__ void gload16(const void* g, void* l) {
    __builtin_amdgcn_global_load_lds(
        (const __attribute__((address_space(1))) unsigned int*)g,
        (__attribute__((address_space(3))) unsigned int*)l, 16, 0, 0);
}

// ---- prep: W matrices -> bf16, transposed [N][256] -------------------------
// Wt rows: [0,256) = W_val^T; [256,832) = [W_off|W_attn]^T; [832,1088) = W_out^T
__global__ __launch_bounds__(256) void prep_w(
    const float* __restrict__ Wv, const float* __restrict__ Woff,
    const float* __restrict__ Wattn, const float* __restrict__ Wo,
    unsigned short* __restrict__ Wt)
{
    const int id = blockIdx.x * 256 + threadIdx.x;   // < 1088*256
    const int n = id >> 8, k = id & 255;
    float val;
    if (n < 256) val = Wv[k * 256 + n];
    else if (n < 832) {
        const int nn = n - 256;
        val = (nn < 384) ? Woff[k * 384 + nn] : Wattn[k * 192 + (nn - 384)];
    } else val = Wo[k * 256 + (n - 832)];
    Wt[id] = f2bf(val);
}

// ---- q = bf16(query + query_pos) ------------------------------------------
__global__ __launch_bounds__(256) void q_conv(
    const float* __restrict__ query, const float* __restrict__ qpos,
    unsigned short* __restrict__ qbf)
{
    const long i = ((long)blockIdx.x * 256 + threadIdx.x) * 4;
    const float4 a = *(const float4*)(query + i);
    const float4 b = *(const float4*)(qpos + i);
    ushort4 r;
    r.x = f2bf(a.x + b.x); r.y = f2bf(a.y + b.y);
    r.z = f2bf(a.z + b.z); r.w = f2bf(a.w + b.w);
    *(ushort4*)(qbf + i) = r;
}

// ---- bf16 MFMA GEMM body: C[128,BN] tile = A[128,256] @ Bt[BN,256]^T + b ---
// 512 thr = 8 waves; wave tile 64 x (BN/4). BK=64, single-buffer (R6 struct:
// explicit dbuf regressed in R8 -- LDS doubling cut blocks/CU 3->1; the
// cross-block TLP it destroyed was what hid staging latency, per m99/m114).
// LDS linear [row][64] bf16 (128 B rows), chunk-XOR swizzle:
//   phys chunk = logical chunk ^ (row & 7)   (chunk = 16 B)
// AMODE: 0 = A fp32 (reg-stage + cvt, swizzled ds_write), 1 = A bf16 (DMA).
// OPERAND-SWAPPED MFMA: acc = mfma(bfr, af, acc) -> lane holds 4 consecutive
// output cols of one row -> float4/ushort4 epilogue.
template<int BN, int AMODE, int VTRANS, int RESID, int SPLITB>
__device__ __forceinline__ void gemm_body(
    const void* __restrict__ Av, const unsigned short* __restrict__ Bt,
    const float* __restrict__ bias, const float* __restrict__ bias2,
    const float* __restrict__ resid, void* __restrict__ Cv,
    int bm, int bcol, char* smem, int Ntot)
{
    constexpr int BK = 64, BMt = 128;
    constexpr int WN = BN / 4, NT = WN / 16;
    constexpr int ACH = BMt * (BK / 8);     // A 16B-chunks = 1024
    constexpr int BCH = BN * (BK / 8);      // B 16B-chunks
    constexpr int NCH = ACH + BCH;
    const int tid = threadIdx.x;
    const int wid = tid >> 6, lane = tid & 63;
    const int wm = (wid >> 2) * 64, wn = (wid & 3) * WN;
    const int lm = lane & 15;

    floatx4 acc[4][NT];
#pragma unroll
    for (int i = 0; i < 4; ++i)
#pragma unroll
        for (int j = 0; j < NT; ++j) acc[i][j] = (floatx4)0.0f;

    for (int k0 = 0; k0 < 256; k0 += BK) {
        if (AMODE == 1) {
            const unsigned short* A = (const unsigned short*)Av;
            constexpr int NI = NCH / 512;   // gload instrs per wave
#pragma unroll
            for (int j = 0; j < NI; ++j) {
                const int cbase = (wid * NI + j) * 64;
                const int g = cbase + lane;
                const unsigned short* src;
                if (cbase < ACH) {          // wave-uniform branch (64 | ACH)
                    const int row = g >> 3, c = (g & 7) ^ (row & 7);
                    src = A + (long)(bm + row) * 256 + k0 + c * 8;
                } else {
                    const int g2 = g - ACH;
                    const int row = g2 >> 3, c = (g2 & 7) ^ (row & 7);
                    src = Bt + (long)(bcol + row) * 256 + k0 + c * 8;
                }
                gload16(src, smem + cbase * 16);
            }
        } else {
            // B via async DMA
            constexpr int NIB = BCH / 512;
#pragma unroll
            for (int j = 0; j < NIB; ++j) {
                const int cbase = (wid * NIB + j) * 64;
                const int g2 = cbase + lane;
                const int row = g2 >> 3, c = (g2 & 7) ^ (row & 7);
                gload16(Bt + (long)(bcol + row) * 256 + k0 + c * 8,
                        smem + ACH * 16 + cbase * 16);
            }
            // A fp32 -> bf16 reg-stage (2 chunks per thread), swizzled ds_write
            const float* A = (const float*)Av;
#pragma unroll
            for (int j = 0; j < 2; ++j) {
                const int g = j * 512 + tid;
                const int row = g >> 3, c = g & 7;
                const float* p = A + (long)(bm + row) * 256 + k0 + c * 8;
                const float4 a = *(const float4*)p;
                const float4 b = *(const float4*)(p + 4);
                uint4 v;
                v.x = pack2(a.x, a.y); v.y = pack2(a.z, a.w);
                v.z = pack2(b.x, b.y); v.w = pack2(b.z, b.w);
                *(uint4*)(smem + row * 128 + ((c ^ (row & 7)) << 4)) = v;
            }
        }
        __syncthreads();

#pragma unroll
        for (int kk = 0; kk < 2; ++kk) {
            const int cc = kk * 4 + (lane >> 4);   // logical 16B chunk in row
            short8 af[4], bfr[NT];
#pragma unroll
            for (int i = 0; i < 4; ++i) {
                const int row = wm + i * 16 + lm;
                af[i] = *(const short8*)(smem + row * 128 + ((cc ^ (row & 7)) << 4));
            }
#pragma unroll
            for (int j = 0; j < NT; ++j) {
                const int row = wn + j * 16 + lm;
                bfr[j] = *(const short8*)(smem + ACH * 16 + row * 128 + ((cc ^ (row & 7)) << 4));
            }
#pragma unroll
            for (int i = 0; i < 4; ++i)
#pragma unroll
                for (int j = 0; j < NT; ++j)
                    acc[i][j] = __builtin_amdgcn_mfma_f32_16x16x32_bf16(bfr[j], af[i], acc[i][j], 0, 0, 0);
        }
        __syncthreads();
    }

    // ---- vectorized epilogue: lane holds 4 consecutive cols of one row ----
    const int qrow = (lane >> 4) * 4;
#pragma unroll
    for (int j = 0; j < NT; ++j) {
        const int colg = bcol + wn + j * 16 + qrow;   // cols colg .. colg+3
        float4 bv4;
        if (SPLITB && colg >= 384) bv4 = *(const float4*)(bias2 + colg - 384);
        else                       bv4 = *(const float4*)(bias + colg);
#pragma unroll
        for (int i = 0; i < 4; ++i) {
            const int rowl = wm + i * 16 + lm;
            const int rowg = bm + rowl;
            float v0 = acc[i][j][0] + bv4.x;
            float v1 = acc[i][j][1] + bv4.y;
            float v2 = acc[i][j][2] + bv4.z;
            float v3 = acc[i][j][3] + bv4.w;
            if (VTRANS) {
                // bf16 v in [b][h][pos][32]; 128 | NVAL so block is one batch.
                // 4 consecutive cols stay within one h-plane (4 | 32).
                const int b = bm / NVAL;
                const int pos = bm - b * NVAL + rowl;
                const int h = colg >> 5, d = colg & 31;
                ushort4 o;
                o.x = f2bf(v0); o.y = f2bf(v1); o.z = f2bf(v2); o.w = f2bf(v3);
                *(ushort4*)&((unsigned short*)Cv)[
                    (((long)(b * NHEAD + h)) * NVAL + pos) * 32 + d] = o;
            } else {
                if (RESID) {
                    const float4 rr = *(const float4*)(resid + (long)rowg * 256 + colg);
                    v0 += rr.x; v1 += rr.y; v2 += rr.z; v3 += rr.w;
                }
                float4 o; o.x = v0; o.y = v1; o.z = v2; o.w = v3;
                *(float4*)&((float*)Cv)[(long)rowg * Ntot + colg] = o;
            }
        }
    }
}

// ---- fused gemm1+gemm2: one dispatch, 672 + 768 = 1440 blocks --------------
// gemm1 (value @ W_val -> v_bf, VTRANS) and gemm2 (q_bf @ [W_off|W_attn] ->
// oa, SPLITB) are independent; fusing them co-locates blocks of BOTH on every
// CU (interleaved 7:8 via id%15) so staging of one overlaps MFMA of the other
// -> duty cycle up (both were ~27%-occupancy latency-bound dispatches).
__global__ __launch_bounds__(512) void gemm_fused(
    const float* __restrict__ value, const unsigned short* __restrict__ qbf,
    const unsigned short* __restrict__ Wt,
    const float* __restrict__ b_val, const float* __restrict__ b_off,
    const float* __restrict__ b_attn,
    unsigned short* __restrict__ v_bf, float* __restrict__ oa)
{
    __shared__ char smem[49152];   // max(gemm1 48K, gemm2 40K)
    const int id = blockIdx.x;     // 1440 = 96 groups of 15 (7 gemm1 + 8 gemm2)
    const int grp = id / 15, r = id % 15;
    if (r < 7) {
        const int t = grp * 7 + r;          // 0..671  (M-tile of gemm1)
        gemm_body<256, 0, 1, 0, 0>(value, Wt, b_val, nullptr, nullptr,
                                   v_bf, t * 128, 0, smem, 256);
    } else {
        const int t = grp * 8 + (r - 7);    // 0..767  (tile of gemm2)
        gemm_body<192, 1, 0, 0, 1>(qbf, Wt + (long)256 * 256, b_off, b_attn,
                                   nullptr, oa, (t / 3) * 128, (t % 3) * 192,
                                   smem, 576);
    }
}

// ---- gemm3: out = interm @ W_out + b_out + query ---------------------------
// BN=128, grid (2, 256) = 512 blocks (~2/CU vs exactly 1 at BN=256): the A
// re-read this costs is +16 MB of L3-resident bf16 (cheap), unlike R7's
// gemm1 split which re-read 88 MB fp32 (that's why it failed there).
__global__ __launch_bounds__(512) void gemm3_k(
    const unsigned short* __restrict__ ibf, const unsigned short* __restrict__ Wt,
    const float* __restrict__ b_out, const float* __restrict__ query,
    float* __restrict__ out)
{
    __shared__ char smem[32768];
    gemm_body<128, 1, 0, 1, 0>(ibf, Wt, b_out, nullptr, query, out,
                               blockIdx.y * 128, blockIdx.x * 128, smem, 256);
}

// ---- deformable sampling (wave per query, bf16 v, bf16 out) ----------------
// 256 thr = 4 waves = 4 queries. lane: head h = lane>>3, li = lane&7.
// v: bf16 [b][h][pos][32]; oa row: [off(384) | attn(192)] fp32.
// (XCD-batch pinning tried in R7: FETCH -33% but dur +6% -> reverted.)
//
// Two-phase. Phase 1: each lane owns 3 samples of its head; softmax via 8-lane
// shfl tree; per sample compute geometry ONCE and store a 24-B record
// {w0l,w1l,w0r,w1r, byteoff_row0, byteoff_row1} in LDS. The two x-corners of a
// bilinear row are adjacent 64-B blocks -> one 128-B contiguous region starting
// at xb=clamp(x0,0,W-2); corner weights re-assigned so the extra column gets 0.
// Phase 2: per (lp,row) ONE dwordx4 gather (8 lanes x 16B = 128B: lanes 0-3 =
// left corner ch li*8..+7, lanes 4-7 = right corner). Corner-side partials
// summed at the end via shfl_xor(4).
__global__ __launch_bounds__(256) void ms_sample4(
    const unsigned short* __restrict__ v,
    const float* __restrict__ oa,
    const float* __restrict__ refp,
    unsigned short* __restrict__ outi)
{
    __shared__ float s_rec[4][192 * 6];   // [wave][ (lp*8+h)*6 ] : 4x4608 B
    __shared__ float s_ref[4][12];
    const int tid = threadIdx.x;
    const int w = tid >> 6;
    const int lane = tid & 63;
    const int bq = blockIdx.x * 4 + w;
    const int b = bq >> 12;

    if (lane < 12) s_ref[w][lane] = refp[(long)bq * 12 + lane];
    __syncthreads();

    const int h = lane >> 3;
    const int li = lane & 7;
    const float* oarow = oa + (long)bq * 576;

    // ---- phase 1a: softmax over this head's 24 logits (3 per lane) --------
    const float* lgp = oarow + 384 + h * 24 + li * 3;
    const float lg0 = lgp[0], lg1 = lgp[1], lg2 = lgp[2];
    float mx = fmaxf(lg0, fmaxf(lg1, lg2));
    mx = fmaxf(mx, __shfl_xor(mx, 1));
    mx = fmaxf(mx, __shfl_xor(mx, 2));
    mx = fmaxf(mx, __shfl_xor(mx, 4));
    const float e0 = __expf(lg0 - mx);
    const float e1 = __expf(lg1 - mx);
    const float e2 = __expf(lg2 - mx);
    float den = e0 + e1 + e2;
    den += __shfl_xor(den, 1);
    den += __shfl_xor(den, 2);
    den += __shfl_xor(den, 4);
    const float inv = 1.0f / den;
    const float aw_[3] = {e0 * inv, e1 * inv, e2 * inv};

    // ---- phase 1b: geometry + fused weights for 3 owned samples -----------
    const float* offp = oarow + (h * 24 + li * 3) * 2;   // 8-B aligned
    const float2v od0 = *(const float2v*)(offp);
    const float2v od1 = *(const float2v*)(offp + 2);
    const float2v od2 = *(const float2v*)(offp + 4);

#pragma unroll
    for (int k = 0; k < 3; ++k) {
        const int lp = li * 3 + k;
        const int l = lp >> 2;
        const int sh = (l >= 3) ? (l - 3) : l;
        const int W = 64 >> sh;
        const int base = ((l >= 3) ? 5376 : 0)
                       + ((sh >= 1) ? 4096 : 0)
                       + ((sh >= 2) ? 1024 : 0);
        const float Wf = (float)W;
        const float ox = (k == 0) ? od0.x : (k == 1) ? od1.x : od2.x;
        const float oy = (k == 0) ? od0.y : (k == 1) ? od1.y : od2.y;
        const float rx = s_ref[w][l * 2 + 0];
        const float ry = s_ref[w][l * 2 + 1];
        const float x = rx * Wf + ox - 0.5f;   // == ((rx + ox/W)*W - 0.5), pow2
        const float y = ry * Wf + oy - 0.5f;
        const float xf = floorf(x), yf = floorf(y);
        const int x0 = (int)xf, y0 = (int)yf;
        const float lx = x - xf, ly = y - yf;
        const float wx0 = (x0 >= 0 && x0 < W)      ? (1.f - lx) : 0.f;
        const float wx1 = (x0 >= -1 && x0 < W - 1) ? lx         : 0.f;
        const float wy0 = (y0 >= 0 && y0 < W)      ? (1.f - ly) : 0.f;
        const float wy1 = (y0 >= -1 && y0 < W - 1) ? ly         : 0.f;
        const int y0c = min(max(y0, 0), W - 1);
        const int y1c = min(max(y0 + 1, 0), W - 1);
        // x: load 128-B region [xb, xb+1]; re-assign corner weights so the
        // padded column carries weight 0 (OOB corners have wx==0 already).
        const int xb = min(max(x0, 0), W - 2);
        const float wl = (xb == x0) ? wx0 : ((xb == x0 + 1) ? wx1 : 0.f);
        const float wr = (xb == x0) ? wx1 : ((xb == x0 - 1) ? wx0 : 0.f);
        const float aw = aw_[k];
        const float awl = aw * wl, awr = aw * wr;
        float* r = &s_rec[w][((lp << 3) + h) * 6];
        float2v wlv, wrv;
        wlv.x = awl * wy0; wlv.y = awl * wy1;   // (row0, row1) left corner
        wrv.x = awr * wy0; wrv.y = awr * wy1;   // (row0, row1) right corner
        *(float2v*)(r)     = wlv;
        *(float2v*)(r + 2) = wrv;
        uint2 pk;
        pk.x = (unsigned)(base + y0c * W + xb) * 64u;   // byte offset, row0
        pk.y = (unsigned)(base + y1c * W + xb) * 64u;   // byte offset, row1
        *(uint2*)(r + 4) = pk;
    }
    __syncthreads();

    // ---- phase 2: gather + accumulate (packed f32) ------------------------
    // lane carries 8 channels [(li&3)*8 .. +7] of ONE corner side (li<4 left).
    const unsigned lane_base =
        (unsigned)((b * NHEAD + h) * NVAL) * 64u + (unsigned)li * 16u;
    const char* vbase = (const char*)v;
    const int sel = (li >> 2) * 2;            // weight pair: 0=left, 2=right
    const float* rp0 = &s_rec[w][h * 6];
    float2v a01 = {0.f, 0.f}, a23 = {0.f, 0.f};
    float2v a45 = {0.f, 0.f}, a67 = {0.f, 0.f};

#pragma unroll 8
    for (int lp = 0; lp < NLVL * NPOINT; ++lp) {
        const float* rp = rp0 + lp * 48;
        const float2v wv = *(const float2v*)(rp + sel);   // (w_row0, w_row1)
        const uint2 off = *(const uint2*)(rp + 4);
        const uint4 u0 = *(const uint4*)(vbase + (lane_base + off.x));
        const uint4 u1 = *(const uint4*)(vbase + (lane_base + off.y));
        float2v c;
        c.x = blo(u0.x); c.y = bhi(u0.x); a01 += wv.x * c;
        c.x = blo(u0.y); c.y = bhi(u0.y); a23 += wv.x * c;
        c.x = blo(u0.z); c.y = bhi(u0.z); a45 += wv.x * c;
        c.x = blo(u0.w); c.y = bhi(u0.w); a67 += wv.x * c;
        c.x = blo(u1.x); c.y = bhi(u1.x); a01 += wv.y * c;
        c.x = blo(u1.y); c.y = bhi(u1.y); a23 += wv.y * c;
        c.x = blo(u1.z); c.y = bhi(u1.z); a45 += wv.y * c;
        c.x = blo(u1.w); c.y = bhi(u1.w); a67 += wv.y * c;
    }

    // combine left/right corner partials (same channels in lane li and li^4)
    a01.x += __shfl_xor(a01.x, 4); a01.y += __shfl_xor(a01.y, 4);
    a23.x += __shfl_xor(a23.x, 4); a23.y += __shfl_xor(a23.y, 4);
    a45.x += __shfl_xor(a45.x, 4); a45.y += __shfl_xor(a45.y, 4);
    a67.x += __shfl_xor(a67.x, 4); a67.y += __shfl_xor(a67.y, 4);

    // output: lane li<4 writes ch (li&3)*8 + 0..3, lane li>=4 writes +4..7
    const int hi = li >> 2;
    const float o0 = hi ? a45.x : a01.x;
    const float o1 = hi ? a45.y : a01.y;
    const float o2 = hi ? a67.x : a23.x;
    const float o3 = hi ? a67.y : a23.y;
    ushort4 o;
    o.x = f2bf(o0); o.y = f2bf(o1); o.z = f2bf(o2); o.w = f2bf(o3);
    const int d = (li & 3) * 8 + hi * 4;
    *(ushort4*)(outi + (long)bq * CDIM + h * 32 + d) = o;
}

// ---------------- launch ---------------------------------------------------
extern "C" void kernel_launch(void* const* d_in, const int* in_sizes, int n_in,
                              void* d_out, int out_size, void* d_ws, size_t ws_size,
                              hipStream_t stream) {
    const float* query     = (const float*)d_in[0];
    const float* query_pos = (const float*)d_in[1];
    const float* value     = (const float*)d_in[2];
    const float* refp      = (const float*)d_in[3];
    // d_in[4] = spatial_shapes (static, hard-coded)
    const float* W_off  = (const float*)d_in[5];
    const float* b_off  = (const float*)d_in[6];
    const float* W_attn = (const float*)d_in[7];
    const float* b_attn = (const float*)d_in[8];
    const float* W_val  = (const float*)d_in[9];
    const float* b_val  = (const float*)d_in[10];
    const float* W_out  = (const float*)d_in[11];
    const float* b_out  = (const float*)d_in[12];
    float* out = (float*)d_out;

    // workspace: all bf16 buffers as ushort
    unsigned short* v_bf = (unsigned short*)d_ws;            // 86016*256 bf16 [b][h][pos][32]
    unsigned short* q_bf = v_bf + (long)86016 * 256;         // 32768*256 bf16
    unsigned short* Wt   = q_bf + (long)32768 * 256;         // 1088*256 bf16 (transposed W's)
    float* oa_ws = (float*)(Wt + (long)1088 * 256);          // 32768*576 fp32 [off|attn]
    unsigned short* i_bf = (unsigned short*)(oa_ws + (long)32768 * 576);  // 32768*256 bf16

    const int MQ = BSZ * NQRY;   // 32768

    // W -> bf16 transposed
    prep_w<<<1088, 256, 0, stream>>>(W_val, W_off, W_attn, W_out, Wt);
    // q = bf16(query + query_pos)
    q_conv<<<(MQ * CDIM / 4) / 256, 256, 0, stream>>>(query, query_pos, q_bf);
    // fused: v = value @ W_val + b_val -> v_bf  ||  oa = q @ [W_off|W_attn]+b
    gemm_fused<<<1440, 512, 0, stream>>>(
        value, q_bf, Wt, b_val, b_off, b_attn, v_bf, oa_ws);
    // deformable sampling -> interm bf16
    ms_sample4<<<MQ / 4, 256, 0, stream>>>(v_bf, oa_ws, refp, i_bf);
    // out = interm @ W_out + b_out + query
    gemm3_k<<<dim3(2, MQ / 128), 512, 0, stream>>>(
        i_bf, Wt + (long)832 * 256, b_out, query, out);
}